// Round 1
// 229.849 us; speedup vs baseline: 1.0873x; 1.0873x over previous
//
#include <hip/hip_runtime.h>

typedef __bf16 bf16x8 __attribute__((ext_vector_type(8)));
typedef __bf16 bf16x4 __attribute__((ext_vector_type(4)));
typedef float  floatx4 __attribute__((ext_vector_type(4)));

#define GLOBAL_AS __attribute__((address_space(1)))
#define LOCAL_AS  __attribute__((address_space(3)))

static constexpr int HID = 1024;
static constexpr int MT  = 128;  // samples per block
static constexpr int BK  = 64;   // K per staging iter
static constexpr int KIT = HID / BK;  // 16

__device__ __forceinline__ void h8(bf16x8& d, float s0, float s1,
                                   const float4& w0a, const float4& w0b,
                                   const float4& w1a, const float4& w1b,
                                   const float4& ba,  const float4& bb) {
    d[0] = (__bf16)fmaxf(fmaf(s1, w1a.x, fmaf(s0, w0a.x, ba.x)), 0.f);
    d[1] = (__bf16)fmaxf(fmaf(s1, w1a.y, fmaf(s0, w0a.y, ba.y)), 0.f);
    d[2] = (__bf16)fmaxf(fmaf(s1, w1a.z, fmaf(s0, w0a.z, ba.z)), 0.f);
    d[3] = (__bf16)fmaxf(fmaf(s1, w1a.w, fmaf(s0, w0a.w, ba.w)), 0.f);
    d[4] = (__bf16)fmaxf(fmaf(s1, w1b.x, fmaf(s0, w0b.x, bb.x)), 0.f);
    d[5] = (__bf16)fmaxf(fmaf(s1, w1b.y, fmaf(s0, w0b.y, bb.y)), 0.f);
    d[6] = (__bf16)fmaxf(fmaf(s1, w1b.z, fmaf(s0, w0b.z, bb.z)), 0.f);
    d[7] = (__bf16)fmaxf(fmaf(s1, w1b.w, fmaf(s0, w0b.w, bb.w)), 0.f);
}

// ---------------------------------------------------------------------------
// prep: H materialization REMOVED (layer 1 is fused into policy_main — H is
// rank-3 in s, recomputing it on the fly is ~24 us of overlappable VALU vs
// a 134 MB write + 504 MB re-read). Remaining jobs:
//   [0, 256)    : zero OUT (65536 x 4 f32, one float4/thread)
//   [256, 512)  : W2 -> W2T (r1-verified, K-octet swizzle baked in)
//   [512, 544)  : W_heads -> WHT (r2-verified)
// Weight preps LAST: W2T/WHT land freshly in L2 right before policy_main.
// ---------------------------------------------------------------------------
__global__ __launch_bounds__(256)
void prep_all(const float* __restrict__ W2, const float* __restrict__ WH,
              __bf16* __restrict__ W2T, __bf16* __restrict__ WHT,
              float* __restrict__ OUT) {
    int b = blockIdx.x;
    if (b < 256) {
        // ---- zero OUT (one float4 = one sample)
        ((float4*)OUT)[(size_t)b * 256 + threadIdx.x]
            = make_float4(0.f, 0.f, 0.f, 0.f);
        return;
    }
    b -= 256;
    if (b < 256) {
        // ---- W2 [K][N] fp32 -> W2T [N][K] bf16, octet g stored at g^(n&7)
        __shared__ __bf16 tile[64][65];
        const int bx = b & 15;   // n-tile
        const int by = b >> 4;   // k-tile
        const int a  = threadIdx.x & 63;
        const int bb = threadIdx.x >> 6;  // 0..3
#pragma unroll
        for (int r = 0; r < 16; ++r) {
            const int k = r * 4 + bb;
            tile[a][k] = (__bf16)W2[(size_t)(by * 64 + k) * HID + bx * 64 + a];
        }
        __syncthreads();
#pragma unroll
        for (int r = 0; r < 16; ++r) {
            const int n = r * 4 + bb;
            const int g = a >> 3, j = a & 7;
            const int ksw = ((g ^ (n & 7)) << 3) | j;
            W2T[(size_t)(bx * 64 + n) * HID + by * 64 + ksw] = tile[n][a];
        }
    } else {
        // ---- W_heads [5][H][4] -> WHT [32][H] bf16 (rows 20..31 zero)
        const int r = b - 256;             // 0..31
        const int s = r >> 2, a = r & 3;
        for (int k = threadIdx.x; k < HID; k += 256) {
            const float v = (r < 20) ? WH[((size_t)s * HID + k) * 4 + a] : 0.f;
            const int c = k >> 7, o = (k >> 3) & 15, j = k & 7;
            const int sw = (o & 8) | ((o & 7) ^ (r & 7));
            WHT[(size_t)r * HID + c * 128 + sw * 8 + j] = (__bf16)v;
        }
    }
}

// ---------------------------------------------------------------------------
// m97-form GEMM + fused head, with layer-1 FUSED: the A tile (H) is computed
// in-register from S (2 floats/sample, held in VGPRs) + the kt-slab of
// W1/b1 (6 L1-hit float4 loads/lane, 8-lane oct groups share addresses),
// then ds_write_b128 into hA with the SAME octet swizzle the frag reads
// expect ((oct^(smp&7))<<3). Bt staging via global_load_lds unchanged.
// The ~128 VALU instrs of H-compute sit between the Bt issue and the
// drain barrier — they hide the load latency that used to be pure stall.
// 256 threads / 4 waves, 128x128 tile, BK=64, LDS 40960 B -> 4 blocks/CU.
// No chunking: workspace only holds W2T+WHT (2.1 MB).
// ---------------------------------------------------------------------------
__global__ __launch_bounds__(256, 4)
void policy_main(const float* __restrict__ S,  const int* __restrict__ SK,
                 const float* __restrict__ W1, const float* __restrict__ B1,
                 const __bf16* __restrict__ W2T, const float* __restrict__ B2,
                 const __bf16* __restrict__ WHT, const float* __restrict__ BH,
                 float* __restrict__ OUT) {
    __shared__ __align__(16) char smem[40960];
    __bf16* hA    = (__bf16*)smem;            // [128][64] swizzled
    __bf16* Bt    = (__bf16*)(smem + 16384);  // [128][64]
    __bf16* featL = (__bf16*)smem;            // overlay [128][128] swizzled
    __bf16* WHTL  = (__bf16*)(smem + 32768);  // [32][128]

    const int tid  = threadIdx.x;
    const int lane = tid & 63;
    const int wv   = tid >> 6;   // 0..3
    const int wm   = wv & 1;     // sample strip of 64
    const int wn   = wv >> 1;    // featcol strip of 64
    const int l15  = lane & 15;
    const int quad = lane >> 4;
    const int n8   = blockIdx.x >> 9;          // 0..7 feature slab
    const int i0l  = (blockIdx.x & 511) * MT;  // sample base

    const int a8  = lane & 7;    // H-compute: sample sub-index
    const int oct = lane >> 3;   // H-compute: column octet 0..7

    floatx4 acc[4][4] = {};    // [fn featcol-frag][fm sample-frag]
    floatx4 hacc[2][2] = {};   // head acc [sample-frag][headcol-tile]

    // ---- prologue: stage WHTL [32][128] once (kt-invariant)
#pragma unroll
    for (int c = 0; c < 2; ++c) {
        const int rb = c * 16 + wv * 4;
        const __bf16* gp = WHT + (size_t)(rb + (lane >> 4)) * HID
                         + n8 * 128 + (lane & 15) * 8;
        __builtin_amdgcn_global_load_lds((GLOBAL_AS void*)gp,
                                         (LOCAL_AS void*)(WHTL + rb * 128), 16, 0, 0);
    }

    // ---- prologue: this lane's 4 sample states (wave wv owns rows wv*32..+31)
    float2 sv[4];
#pragma unroll
    for (int k = 0; k < 4; ++k)
        sv[k] = *(const float2*)(S + (size_t)(i0l + wv * 32 + a8 + 8 * k) * 2);

#pragma unroll 1
    for (int kt = 0; kt < KIT; ++kt) {
        __syncthreads();  // previous iter's frag readers done
        // ---- stage B from W2T slab n8 (issue first: longest latency)
#pragma unroll
        for (int c = 0; c < 4; ++c) {
            const int rb = c * 32 + wv * 8;
            const __bf16* gp = W2T + (size_t)(n8 * 128 + rb + (lane >> 3)) * HID
                             + kt * BK + (lane & 7) * 8;
            __builtin_amdgcn_global_load_lds((GLOBAL_AS void*)gp,
                                             (LOCAL_AS void*)(Bt + rb * 64), 16, 0, 0);
        }
        // ---- compute A tile (H) in-register, write swizzled to hA.
        //      lane: octet `oct` of the kt-slab, samples a8+8k (k=0..3).
        //      W slab loads are L1/L2 hits (12 KB total), 8 lanes/addr.
        {
            const float4 w0a = *(const float4*)(W1 + kt * BK + oct * 8);
            const float4 w0b = *(const float4*)(W1 + kt * BK + oct * 8 + 4);
            const float4 w1a = *(const float4*)(W1 + HID + kt * BK + oct * 8);
            const float4 w1b = *(const float4*)(W1 + HID + kt * BK + oct * 8 + 4);
            const float4 ba  = *(const float4*)(B1 + kt * BK + oct * 8);
            const float4 bb  = *(const float4*)(B1 + kt * BK + oct * 8 + 4);
#pragma unroll
            for (int k = 0; k < 4; ++k) {
                const int smp = wv * 32 + a8 + 8 * k;
                bf16x8 hv;
                h8(hv, sv[k].x, sv[k].y, w0a, w0b, w1a, w1b, ba, bb);
                // smp&7 == a8, so swizzle == (oct ^ (smp&7)) — matches frag read
                *(bf16x8*)(hA + smp * 64 + ((oct ^ a8) << 3)) = hv;
            }
        }
        __syncthreads();  // drain Bt staging + hA writes
        // ---- 2 k-steps of 32: 8 frag reads + 16 MFMA each
#pragma unroll
        for (int ks = 0; ks < 2; ++ks) {
            bf16x8 wf[4], hf[4];
#pragma unroll
            for (int f = 0; f < 4; ++f) {
                const int row = wn * 64 + f * 16 + l15;   // featcol (local)
                wf[f] = *(const bf16x8*)(Bt + row * 64 + (((ks * 4 + quad) ^ (row & 7)) * 8));
            }
#pragma unroll
            for (int f = 0; f < 4; ++f) {
                const int smp = wm * 64 + f * 16 + l15;
                hf[f] = *(const bf16x8*)(hA + smp * 64 + (((ks * 4 + quad) ^ (smp & 7)) * 8));
            }
#pragma unroll
            for (int fn = 0; fn < 4; ++fn)
#pragma unroll
                for (int fm = 0; fm < 4; ++fm)
                    acc[fn][fm] = __builtin_amdgcn_mfma_f32_16x16x32_bf16(
                        wf[fn], hf[fm], acc[fn][fm], 0, 0, 0);
        }
    }

    // ---- epilogue: relu(acc+b2) -> featL (swizzled, overlays hA+Bt)
    __syncthreads();  // K-loop frag readers done before overlay
#pragma unroll
    for (int fn = 0; fn < 4; ++fn) {
        const int fcb = wn * 64 + fn * 16 + quad * 4;   // featcol base 0..124
        const float4 b2v = *(const float4*)(B2 + n8 * 128 + fcb);
#pragma unroll
        for (int fm = 0; fm < 4; ++fm) {
            const int smp = wm * 64 + fm * 16 + l15;
            const floatx4 v = acc[fn][fm];
            bf16x4 p;
            p[0] = (__bf16)fmaxf(v[0] + b2v.x, 0.f);
            p[1] = (__bf16)fmaxf(v[1] + b2v.y, 0.f);
            p[2] = (__bf16)fmaxf(v[2] + b2v.z, 0.f);
            p[3] = (__bf16)fmaxf(v[3] + b2v.w, 0.f);
            *(bf16x4*)(featL + smp * 128 + (((fcb >> 3) ^ (smp & 15)) << 3) + (fcb & 7)) = p;
        }
    }
    __syncthreads();

    // ---- head MFMA: wave w -> samples w*32..+31, K = this block's 128 cols
#pragma unroll
    for (int f2 = 0; f2 < 2; ++f2) {
#pragma unroll
        for (int ks2 = 0; ks2 < 4; ++ks2) {
            const int row = wv * 32 + f2 * 16 + l15;
            const bf16x8 fa = *(const bf16x8*)(featL + row * 128
                                 + (((ks2 * 4 + quad) ^ (row & 15)) << 3));
#pragma unroll
            for (int t2 = 0; t2 < 2; ++t2) {
                const int r = t2 * 16 + l15;
                const int o = ks2 * 4 + quad;
                const int sw = (o & 8) | ((o & 7) ^ (r & 7));
                const bf16x8 wb = *(const bf16x8*)(WHTL + r * 128 + sw * 8);
                hacc[f2][t2] = __builtin_amdgcn_mfma_f32_16x16x32_bf16(
                    fa, wb, hacc[f2][t2], 0, 0, 0);
            }
        }
    }

    // ---- atomic scatter from registers: C-layout sample = quad*4+reg,
    //      headcol = t2*16 + l15; emit only the selected skill's 4 actions
#pragma unroll
    for (int f2 = 0; f2 < 2; ++f2)
#pragma unroll
        for (int j = 0; j < 4; ++j) {
            const int smp = wv * 32 + f2 * 16 + quad * 4 + j;
            const int sk  = SK[(size_t)i0l + smp];
#pragma unroll
            for (int t2 = 0; t2 < 2; ++t2) {
                const int hc = t2 * 16 + l15;
                const int d  = hc - sk * 4;
                if (d >= 0 && d < 4) {
                    float v = hacc[f2][t2][j];
                    if (n8 == 0) v += BH[hc];
                    atomicAdd(&OUT[(size_t)(i0l + smp) * 4 + d], v);
                }
            }
        }
}

extern "C" void kernel_launch(void* const* d_in, const int* in_sizes, int n_in,
                              void* d_out, int out_size, void* d_ws, size_t ws_size,
                              hipStream_t stream) {
    const float* S  = (const float*)d_in[0];
    const int*   SK = (const int*)d_in[1];
    const float* W1 = (const float*)d_in[2];
    const float* B1 = (const float*)d_in[3];
    const float* W2 = (const float*)d_in[4];
    const float* B2 = (const float*)d_in[5];
    const float* WH = (const float*)d_in[6];
    const float* BH = (const float*)d_in[7];

    char* ws = (char*)d_ws;
    __bf16* W2T = (__bf16*)ws;                          // 2 MiB
    __bf16* WHT = (__bf16*)(ws + 2 * 1024 * 1024);      // 64 KiB

    // H is never materialized: layer 1 is recomputed inside policy_main.
    hipLaunchKernelGGL(prep_all, dim3(256 + 256 + 32), dim3(256), 0, stream,
                       W2, WH, W2T, WHT, (float*)d_out);
    hipLaunchKernelGGL(policy_main, dim3((65536 / MT) * 8), dim3(256), 0, stream,
                       S, SK, W1, B1, W2T, B2, WHT, BH, (float*)d_out);
}